// Round 1
// baseline (233.785 us; speedup 1.0000x reference)
//
#include <hip/hip_runtime.h>
#include <hip/hip_bf16.h>

#define RCOEF 1.0f
#define P1    0.5f

__global__ __launch_bounds__(256) void loss_kernel(
    const float* __restrict__ final_out,
    const int*   __restrict__ point_victor,
    float*       __restrict__ out,
    int n, float denom)
{
    const long long tid    = (long long)blockIdx.x * blockDim.x + threadIdx.x;
    const long long stride = (long long)gridDim.x * blockDim.x;

    const float4* fo4 = (const float4*)final_out;
    const int4*   pv4 = (const int4*)point_victor;
    const long long ngroups = n >> 2;   // groups of 4 points

    double acc = 0.0;

    for (long long g = tid; g < ngroups; g += stride) {
        float4 a = fo4[2 * g];       // points 4g, 4g+1  (p0,p1 each)
        float4 b = fo4[2 * g + 1];   // points 4g+2, 4g+3
        int4   v = pv4[g];

        float pw0 = (v.x == 0) ? a.x : a.y;
        float pw1 = (v.y == 0) ? a.z : a.w;
        float pw2 = (v.z == 0) ? b.x : b.y;
        float pw3 = (v.w == 0) ? b.z : b.w;

        float d0 = a.x - P1, d1 = a.z - P1, d2 = b.x - P1, d3 = b.z - P1;

        float e0 = logf(pw0) - RCOEF * d0 * d0;
        float e1 = logf(pw1) - RCOEF * d1 * d1;
        float e2 = logf(pw2) - RCOEF * d2 * d2;
        float e3 = logf(pw3) - RCOEF * d3 * d3;

        float i0 = (float)(g << 2);           // exact for g<<2 < 2^24 repr; matches f32 arange rounding
        float r0 = i0 / denom;
        float r1 = (float)((g << 2) + 1) / denom;
        float r2 = (float)((g << 2) + 2) / denom;
        float r3 = (float)((g << 2) + 3) / denom;

        acc += (double)(e0 * r0 + e1 * r1) + (double)(e2 * r2 + e3 * r3);
    }

    // scalar tail (n not multiple of 4)
    for (long long i = (ngroups << 2) + tid; i < n; i += stride) {
        float p0 = final_out[2 * i];
        float p1v = final_out[2 * i + 1];
        float pw = (point_victor[i] == 0) ? p0 : p1v;
        float d  = p0 - P1;
        float e  = logf(pw) - RCOEF * d * d;
        float r  = (float)i / denom;
        acc += (double)(e * r);
    }

    // wave-64 butterfly reduce (double)
    for (int off = 32; off > 0; off >>= 1)
        acc += __shfl_down(acc, off, 64);

    __shared__ double warp_sums[4];   // 256 threads / 64
    const int wave = threadIdx.x >> 6;
    if ((threadIdx.x & 63) == 0) warp_sums[wave] = acc;
    __syncthreads();

    if (threadIdx.x == 0) {
        double s = warp_sums[0] + warp_sums[1] + warp_sums[2] + warp_sums[3];
        atomicAdd(out, -(float)s);    // loss = -sum
    }
}

extern "C" void kernel_launch(void* const* d_in, const int* in_sizes, int n_in,
                              void* d_out, int out_size, void* d_ws, size_t ws_size,
                              hipStream_t stream) {
    const float* final_out    = (const float*)d_in[0];
    const int*   point_victor = (const int*)d_in[1];
    float*       out          = (float*)d_out;

    const int n = in_sizes[1];   // point_victor has n elements; final_out has 2n

    // denom exactly as the reference computes it in float32:
    // float(n) * float(n+1) * 0.5f
    const float denom = (float)n * (float)(n + 1) * 0.5f;

    hipMemsetAsync(d_out, 0, sizeof(float), stream);

    const int threads = 256;
    const int blocks  = 2048;   // 256 CUs * 8 blocks/CU; grid-stride covers the rest
    loss_kernel<<<blocks, threads, 0, stream>>>(final_out, point_victor, out, n, denom);
}